// Round 2
// baseline (324.614 us; speedup 1.0000x reference)
//
#include <hip/hip_runtime.h>
#include <hip/hip_bf16.h>
#include <math.h>

#define N_SAMPLES 262144
#define DDIM 64
#define KDIM 64

#define LOG2PI 1.8378770664093453f
#define PRIOR_LV0 -2.0f
#define IV0 7.389056098930650f  /* exp(2.0) */

// ws layout (floats):
//   [0, 8192)      : PQ[d][128]  -> [d][0..63] = P'_kd, [d][64..127] = Q_kd   (fp32 staging)
//   [8192, 8256)   : c[k]
//   [8256, 8320)   : logpi[k]
//   [8320, 12416)  : Bsw, 16 KB of bf16 MFMA B-fragments:
//                    frag-set s = kc*4+tile (kc,k-chunk 0..3; tile, col-tile 0..3)
//                    lane l: 8 bf16 = B[kc*32 + (l>>4)*8 + j][tile*16 + (l&15)], j=0..7
//                    where B[j][k] = j<64 ? P'[k][d=j] : Q[k][d=j-64]

typedef __attribute__((ext_vector_type(8))) short short8;
typedef __attribute__((ext_vector_type(4))) float floatx4;

static __device__ inline unsigned short f2bf_bits(float f) {
  union { float f; unsigned u; } v; v.f = f;
  unsigned r = v.u + 0x7fffu + ((v.u >> 16) & 1u);  // RNE
  return (unsigned short)(r >> 16);
}

__global__ __launch_bounds__(256) void setup_kernel(
    const float* __restrict__ u_noise, const float* __restrict__ phi_logits,
    const float* __restrict__ q_mu, const float* __restrict__ q_logvar,
    const float* __restrict__ pi_logits, const float* __restrict__ prior_p,
    float* __restrict__ out, float* __restrict__ ws) {
  __shared__ float sPhi[DDIM];
  __shared__ float sR[DDIM];
  __shared__ float sBeta;
  __shared__ float sPart[4][KDIM];
  int tid = threadIdx.x;

  if (tid < 64) {  // exactly wave 0
    int d = tid;
    float u = u_noise[d];
    float g = -logf(-logf(u + 1e-9f) + 1e-9f);
    float z = phi_logits[d] + g;  // TEMPERATURE = 1.0
    float phi = 1.0f / (1.0f + expf(-z));
    sPhi[d] = phi;
    sR[d] = -0.5f * (1.0f - phi) * IV0;

    float qp = 1.0f / (1.0f + expf(-phi_logits[d]));
    qp = fminf(fmaxf(qp, 1e-6f), 1.0f - 1e-6f);
    out[1 + d] = qp;

    float betap = -0.5f * (1.0f - phi) * (LOG2PI + PRIOR_LV0);
    float pp = fminf(fmaxf(prior_p[d], 1e-6f), 1.0f - 1e-6f);
    float klp = qp * (logf(qp) - logf(pp)) +
                (1.0f - qp) * (logf(1.0f - qp) - logf(1.0f - pp));
    #pragma unroll
    for (int o = 1; o < 64; o <<= 1) {
      betap += __shfl_xor(betap, o, 64);
      klp   += __shfl_xor(klp, o, 64);
    }
    if (d == 0) {
      sBeta = betap;
      out[0] = klp * (float)N_SAMPLES;  // main kernel atomically subtracts LL
    }

    // log(softmax(pi_logits) + 1e-9), K == 64 lanes
    float l = pi_logits[d];
    float m = l;
    #pragma unroll
    for (int o = 1; o < 64; o <<= 1) m = fmaxf(m, __shfl_xor(m, o, 64));
    float e = expf(l - m);
    float s = e;
    #pragma unroll
    for (int o = 1; o < 64; o <<= 1) s += __shfl_xor(s, o, 64);
    ws[8256 + d] = logf(e / s + 1e-9f);
  }
  __syncthreads();

  int k = tid & 63, seg = tid >> 6;
  float ap = 0.0f;
  for (int dd = 0; dd < 16; ++dd) {
    int d = seg * 16 + dd;
    float lv = fminf(fmaxf(q_logvar[k * DDIM + d], -5.0f), 5.0f);
    float iv = expf(-lv);
    float a = sPhi[d] * iv;
    float mu = q_mu[k * DDIM + d];
    ws[d * 128 + k]      = -0.5f * a + sR[d];  // P'
    ws[d * 128 + 64 + k] = mu * a;             // Q
    ap += sPhi[d] * (LOG2PI + lv) + mu * mu * a;
  }
  sPart[seg][k] = ap;
  __syncthreads();
  if (tid < 64) {
    float alpha = sPart[0][tid] + sPart[1][tid] + sPart[2][tid] + sPart[3][tid];
    ws[8192 + tid] = -0.5f * alpha + sBeta;  // c_k
  }

  // B-fragment swizzle for mfma_f32_16x16x32_bf16 (P/Q are ready after 2nd sync)
  unsigned short* bsw = (unsigned short*)(ws + 8320);
  #pragma unroll
  for (int p = 0; p < 4; ++p) {
    int pr = p * 256 + tid;       // (frag-set, lane) pair index, 0..1023
    int s  = pr >> 6;
    int l  = pr & 63;
    int kc = s >> 2, tl = s & 3;
    int q  = l >> 4, nn = l & 15;
    int col = tl * 16 + nn;
    int bk  = kc * 32 + q * 8;
    #pragma unroll
    for (int j = 0; j < 8; ++j) {
      int r = bk + j;
      float val = (r < 64) ? ws[r * 128 + col] : ws[(r - 64) * 128 + 64 + col];
      bsw[pr * 8 + j] = f2bf_bits(val);
    }
  }
}

__global__ __launch_bounds__(256, 4) void gmm_main(
    const float* __restrict__ X, const float* __restrict__ ws,
    float* __restrict__ out) {
  int tid  = threadIdx.x;
  int lane = tid & 63;
  int w    = tid >> 6;
  int n    = lane & 15;   // A-row within tile == C/D column within tile
  int q    = lane >> 4;   // quad
  long rbase = ((long)blockIdx.x * 4 + w) * 16;

  // ---- load X fragment data: row rbase+n, d in [q*8,q*8+8) and [32+q*8, 32+q*8+8)
  const float* xr = X + (rbase + n) * DDIM;
  float4 xa0 = *(const float4*)(xr + q * 8);
  float4 xa1 = *(const float4*)(xr + q * 8 + 4);
  float4 xb0 = *(const float4*)(xr + 32 + q * 8);
  float4 xb1 = *(const float4*)(xr + 32 + q * 8 + 4);

  // ---- build A fragments (bf16x8): kc0 = x^2 lo, kc1 = x^2 hi, kc2 = x lo, kc3 = x hi
  short8 a[4];
  {
    float xa[8] = {xa0.x, xa0.y, xa0.z, xa0.w, xa1.x, xa1.y, xa1.z, xa1.w};
    float xb[8] = {xb0.x, xb0.y, xb0.z, xb0.w, xb1.x, xb1.y, xb1.z, xb1.w};
    #pragma unroll
    for (int j = 0; j < 8; ++j) {
      a[0][j] = (short)f2bf_bits(xa[j] * xa[j]);
      a[1][j] = (short)f2bf_bits(xb[j] * xb[j]);
      a[2][j] = (short)f2bf_bits(xa[j]);
      a[3][j] = (short)f2bf_bits(xb[j]);
    }
  }

  // ---- MFMA: 4 k-chunks x 4 col-tiles
  const short8* Bf = (const short8*)(ws + 8320);
  floatx4 acc[4];
  #pragma unroll
  for (int t = 0; t < 4; ++t) acc[t] = (floatx4){0.f, 0.f, 0.f, 0.f};
  #pragma unroll
  for (int kc = 0; kc < 4; ++kc) {
    #pragma unroll
    for (int t = 0; t < 4; ++t) {
      short8 b = Bf[(kc * 4 + t) * 64 + lane];
      acc[t] = __builtin_amdgcn_mfma_f32_16x16x32_bf16(a[kc], b, acc[t], 0, 0, 0);
    }
  }

  // ---- epilogue: bias + store log_p + LSE reduce
  float cb[4], lpi[4];
  #pragma unroll
  for (int t = 0; t < 4; ++t) {
    cb[t]  = ws[8192 + t * 16 + n];
    lpi[t] = ws[8256 + t * 16 + n];
  }
  float* lp = out + 1 + DDIM;  // float-offset 65
  float rowacc = 0.0f;
  #pragma unroll
  for (int reg = 0; reg < 4; ++reg) {
    long row = rbase + q * 4 + reg;  // C/D row = quad*4 + reg
    float o0 = acc[0][reg] + cb[0];
    float o1 = acc[1][reg] + cb[1];
    float o2 = acc[2][reg] + cb[2];
    float o3 = acc[3][reg] + cb[3];
    long off = row * KDIM + n;
    lp[off]      = o0;
    lp[off + 16] = o1;
    lp[off + 32] = o2;
    lp[off + 48] = o3;
    float v0 = o0 + lpi[0], v1 = o1 + lpi[1], v2 = o2 + lpi[2], v3 = o3 + lpi[3];
    float m = fmaxf(fmaxf(v0, v1), fmaxf(v2, v3));
    #pragma unroll
    for (int o = 1; o <= 8; o <<= 1) m = fmaxf(m, __shfl_xor(m, o, 64));
    float s = __expf(v0 - m) + __expf(v1 - m) + __expf(v2 - m) + __expf(v3 - m);
    #pragma unroll
    for (int o = 1; o <= 8; o <<= 1) s += __shfl_xor(s, o, 64);
    if (n == 0) rowacc += m + __logf(s);
  }
  float t = (n == 0) ? rowacc : 0.0f;
  t += __shfl_xor(t, 16, 64);
  t += __shfl_xor(t, 32, 64);
  if (lane == 0) atomicAdd(out, -t);
}

extern "C" void kernel_launch(void* const* d_in, const int* in_sizes, int n_in,
                              void* d_out, int out_size, void* d_ws, size_t ws_size,
                              hipStream_t stream) {
  const float* X           = (const float*)d_in[0];
  const float* u_noise     = (const float*)d_in[1];
  const float* phi_logits  = (const float*)d_in[2];
  const float* q_mu        = (const float*)d_in[3];
  const float* q_logvar    = (const float*)d_in[4];
  const float* pi_logits   = (const float*)d_in[5];
  const float* prior_p     = (const float*)d_in[6];
  float* out = (float*)d_out;
  float* ws  = (float*)d_ws;

  setup_kernel<<<1, 256, 0, stream>>>(u_noise, phi_logits, q_mu, q_logvar,
                                      pi_logits, prior_p, out, ws);
  // 262144 rows / (4 waves * 16 rows) = 4096 blocks
  gmm_main<<<N_SAMPLES / 64, 256, 0, stream>>>(X, ws, out);
}

// Round 3
// 152.401 us; speedup vs baseline: 2.1300x; 2.1300x over previous
//
#include <hip/hip_runtime.h>
#include <hip/hip_bf16.h>
#include <math.h>

#define N_SAMPLES 262144
#define DDIM 64
#define KDIM 64

#define LOG2PI 1.8378770664093453f
#define PRIOR_LV0 -2.0f
#define IV0 7.389056098930650f  /* exp(2.0) */

typedef __attribute__((ext_vector_type(8))) short short8;
typedef __attribute__((ext_vector_type(4))) float floatx4;

static __device__ inline unsigned short f2bf_bits(float f) {
  union { float f; unsigned u; } v; v.f = f;
  unsigned r = v.u + 0x7fffu + ((v.u >> 16) & 1u);  // RNE
  return (unsigned short)(r >> 16);
}

// Tiny kernel: q_phi + kl_phi, and initializes out[0] (poisoned 0xAA by harness)
// before gmm_main's block atomics accumulate -LL into it.
__global__ __launch_bounds__(64) void kl_kernel(
    const float* __restrict__ phi_logits, const float* __restrict__ prior_p,
    float* __restrict__ out) {
  int d = threadIdx.x;
  float qp = 1.0f / (1.0f + expf(-phi_logits[d]));
  qp = fminf(fmaxf(qp, 1e-6f), 1.0f - 1e-6f);
  out[1 + d] = qp;
  float pp = fminf(fmaxf(prior_p[d], 1e-6f), 1.0f - 1e-6f);
  float klp = qp * (logf(qp) - logf(pp)) +
              (1.0f - qp) * (logf(1.0f - qp) - logf(1.0f - pp));
  #pragma unroll
  for (int o = 1; o < 64; o <<= 1) klp += __shfl_xor(klp, o, 64);
  if (d == 0) out[0] = klp * (float)N_SAMPLES;
}

// Self-contained main kernel. Each block (256 thr, 4 waves) covers 256 rows;
// each wave 64 rows. Per-block redundant setup: phi, B-fragment build (LDS),
// c_k, logpi — reads only ~32KB of params (L2-hot across 1024 blocks).
// One atomicAdd per block (1024 total; round-2 showed 16384 same-address
// atomics serialize at ~14ns each and dominated at 222us).
__global__ __launch_bounds__(256, 3) void gmm_main(
    const float* __restrict__ X, const float* __restrict__ u_noise,
    const float* __restrict__ phi_logits, const float* __restrict__ q_mu,
    const float* __restrict__ q_logvar, const float* __restrict__ pi_logits,
    float* __restrict__ out) {
  __shared__ float sPhi[DDIM];
  __shared__ float sR[DDIM];
  __shared__ float sC[KDIM];
  __shared__ float sLPI[KDIM];
  __shared__ float sPart[4][KDIM];
  __shared__ float sBeta;
  __shared__ float sRed[4];
  __shared__ unsigned short sB[16 * 64 * 8];  // 16 KB of bf16 B-fragments

  int tid  = threadIdx.x;
  int lane = tid & 63;
  int w    = tid >> 6;

  // ---- P1: phi, R, beta, logpi (wave 0 only)
  if (tid < 64) {
    int d = tid;
    float u = u_noise[d];
    float g = -__logf(-__logf(u + 1e-9f) + 1e-9f);
    float phi = 1.0f / (1.0f + __expf(-(phi_logits[d] + g)));  // TEMP=1
    sPhi[d] = phi;
    sR[d] = -0.5f * (1.0f - phi) * IV0;
    float betap = -0.5f * (1.0f - phi) * (LOG2PI + PRIOR_LV0);
    #pragma unroll
    for (int o = 1; o < 64; o <<= 1) betap += __shfl_xor(betap, o, 64);
    if (d == 0) sBeta = betap;
    float l = pi_logits[d];
    float m = l;
    #pragma unroll
    for (int o = 1; o < 64; o <<= 1) m = fmaxf(m, __shfl_xor(m, o, 64));
    float e = __expf(l - m);
    float s = e;
    #pragma unroll
    for (int o = 1; o < 64; o <<= 1) s += __shfl_xor(s, o, 64);
    sLPI[d] = __logf(e / s + 1e-9f);
  }
  __syncthreads();

  // ---- P2: c_k partial sums (256 threads: k = tid&63, d-segment = tid>>6)
  {
    int k = tid & 63, seg = tid >> 6;
    const float* lvp = q_logvar + k * DDIM + seg * 16;
    const float* mup = q_mu + k * DDIM + seg * 16;
    float ap = 0.0f;
    #pragma unroll
    for (int dd = 0; dd < 16; ++dd) {
      int d = seg * 16 + dd;
      float lv = fminf(fmaxf(lvp[dd], -5.0f), 5.0f);
      float iv = __expf(-lv);
      float mu = mup[dd];
      ap += sPhi[d] * (LOG2PI + lv) + mu * mu * sPhi[d] * iv;
    }
    sPart[seg][k] = ap;
  }

  // ---- P3: build bf16 B-fragments directly into LDS
  // frag-set s = kc*4+tl; lane l: 8 bf16 = B[kc*32+(l>>4)*8+j][tl*16+(l&15)]
  // B rows 0..63 = P'[k][d] = -0.5*phi*e^{-lv}+R_d ; rows 64..127 = Q = mu*phi*e^{-lv}
  #pragma unroll
  for (int p = 0; p < 4; ++p) {
    int pr = p * 256 + tid;      // 0..1023 = s*64 + l
    int s = pr >> 6, l = pr & 63;
    int kc = s >> 2, tl = s & 3, q = l >> 4, n = l & 15;
    int k = tl * 16 + n;
    int dbase = (kc & 1) * 32 + q * 8;
    const float* lvp = q_logvar + k * DDIM + dbase;
    float4 lv0 = *(const float4*)lvp;
    float4 lv1 = *(const float4*)(lvp + 4);
    float lvv[8] = {lv0.x, lv0.y, lv0.z, lv0.w, lv1.x, lv1.y, lv1.z, lv1.w};
    short r8[8];
    if (kc < 2) {
      #pragma unroll
      for (int j = 0; j < 8; ++j) {
        int d = dbase + j;
        float lv = fminf(fmaxf(lvv[j], -5.0f), 5.0f);
        float val = -0.5f * sPhi[d] * __expf(-lv) + sR[d];
        r8[j] = (short)f2bf_bits(val);
      }
    } else {
      const float* mup = q_mu + k * DDIM + dbase;
      float4 mu0 = *(const float4*)mup;
      float4 mu1 = *(const float4*)(mup + 4);
      float muv[8] = {mu0.x, mu0.y, mu0.z, mu0.w, mu1.x, mu1.y, mu1.z, mu1.w};
      #pragma unroll
      for (int j = 0; j < 8; ++j) {
        int d = dbase + j;
        float lv = fminf(fmaxf(lvv[j], -5.0f), 5.0f);
        float val = muv[j] * sPhi[d] * __expf(-lv);
        r8[j] = (short)f2bf_bits(val);
      }
    }
    ((short8*)sB)[pr] = (short8){r8[0], r8[1], r8[2], r8[3],
                                 r8[4], r8[5], r8[6], r8[7]};
  }
  __syncthreads();

  // ---- finalize c_k (tid<64) while everyone loads B fragments into regs
  if (tid < 64) {
    sC[tid] = -0.5f * (sPart[0][tid] + sPart[1][tid] +
                       sPart[2][tid] + sPart[3][tid]) + sBeta;
  }
  short8 b[16];
  #pragma unroll
  for (int s = 0; s < 16; ++s) b[s] = ((const short8*)sB)[s * 64 + lane];
  __syncthreads();

  // ---- main: 4 row-tiles of 16 rows per wave
  int n = lane & 15;  // A-row within tile == C/D column within tile
  int q = lane >> 4;  // quad
  long blockbase = (long)blockIdx.x * 256 + (long)w * 64;
  float cb[4], lpi[4];
  #pragma unroll
  for (int t = 0; t < 4; ++t) {
    cb[t]  = sC[t * 16 + n];
    lpi[t] = sLPI[t * 16 + n];
  }
  float* lp = out + 1 + DDIM;  // float-offset 65
  float rowacc = 0.0f;

  #pragma unroll
  for (int rt = 0; rt < 4; ++rt) {
    long rbase = blockbase + rt * 16;
    const float* xr = X + (rbase + n) * DDIM;
    float4 xa0 = *(const float4*)(xr + q * 8);
    float4 xa1 = *(const float4*)(xr + q * 8 + 4);
    float4 xb0 = *(const float4*)(xr + 32 + q * 8);
    float4 xb1 = *(const float4*)(xr + 32 + q * 8 + 4);
    short8 a[4];
    {
      float xa[8] = {xa0.x, xa0.y, xa0.z, xa0.w, xa1.x, xa1.y, xa1.z, xa1.w};
      float xb[8] = {xb0.x, xb0.y, xb0.z, xb0.w, xb1.x, xb1.y, xb1.z, xb1.w};
      #pragma unroll
      for (int j = 0; j < 8; ++j) {
        a[0][j] = (short)f2bf_bits(xa[j] * xa[j]);
        a[1][j] = (short)f2bf_bits(xb[j] * xb[j]);
        a[2][j] = (short)f2bf_bits(xa[j]);
        a[3][j] = (short)f2bf_bits(xb[j]);
      }
    }
    floatx4 acc[4];
    #pragma unroll
    for (int t = 0; t < 4; ++t) acc[t] = (floatx4){0.f, 0.f, 0.f, 0.f};
    #pragma unroll
    for (int kc = 0; kc < 4; ++kc) {
      #pragma unroll
      for (int t = 0; t < 4; ++t)
        acc[t] = __builtin_amdgcn_mfma_f32_16x16x32_bf16(a[kc], b[kc * 4 + t],
                                                         acc[t], 0, 0, 0);
    }
    // epilogue: bias, store, LSE
    #pragma unroll
    for (int reg = 0; reg < 4; ++reg) {
      long row = rbase + q * 4 + reg;  // C/D row = quad*4 + reg
      float o0 = acc[0][reg] + cb[0];
      float o1 = acc[1][reg] + cb[1];
      float o2 = acc[2][reg] + cb[2];
      float o3 = acc[3][reg] + cb[3];
      long off = row * KDIM + n;
      lp[off]      = o0;
      lp[off + 16] = o1;
      lp[off + 32] = o2;
      lp[off + 48] = o3;
      float v0 = o0 + lpi[0], v1 = o1 + lpi[1], v2 = o2 + lpi[2], v3 = o3 + lpi[3];
      float m = fmaxf(fmaxf(v0, v1), fmaxf(v2, v3));
      #pragma unroll
      for (int o = 1; o <= 8; o <<= 1) m = fmaxf(m, __shfl_xor(m, o, 64));
      float sm = __expf(v0 - m) + __expf(v1 - m) + __expf(v2 - m) + __expf(v3 - m);
      #pragma unroll
      for (int o = 1; o <= 8; o <<= 1) sm += __shfl_xor(sm, o, 64);
      if (n == 0) rowacc += m + __logf(sm);
    }
  }

  // ---- block reduce: wave partial -> LDS -> single atomic per block
  float t2 = (n == 0) ? rowacc : 0.0f;
  t2 += __shfl_xor(t2, 16, 64);
  t2 += __shfl_xor(t2, 32, 64);
  if (lane == 0) sRed[w] = t2;
  __syncthreads();
  if (tid == 0) atomicAdd(out, -(sRed[0] + sRed[1] + sRed[2] + sRed[3]));
}

extern "C" void kernel_launch(void* const* d_in, const int* in_sizes, int n_in,
                              void* d_out, int out_size, void* d_ws, size_t ws_size,
                              hipStream_t stream) {
  const float* X           = (const float*)d_in[0];
  const float* u_noise     = (const float*)d_in[1];
  const float* phi_logits  = (const float*)d_in[2];
  const float* q_mu        = (const float*)d_in[3];
  const float* q_logvar    = (const float*)d_in[4];
  const float* pi_logits   = (const float*)d_in[5];
  const float* prior_p     = (const float*)d_in[6];
  float* out = (float*)d_out;

  kl_kernel<<<1, 64, 0, stream>>>(phi_logits, prior_p, out);
  gmm_main<<<N_SAMPLES / 256, 256, 0, stream>>>(X, u_noise, phi_logits, q_mu,
                                                q_logvar, pi_logits, out);
}

// Round 4
// 141.528 us; speedup vs baseline: 2.2936x; 1.0768x over previous
//
#include <hip/hip_runtime.h>
#include <hip/hip_bf16.h>
#include <math.h>

#define N_SAMPLES 262144
#define DDIM 64
#define KDIM 64
#define NBLOCKS 4096

#define LOG2PI 1.8378770664093453f
#define PRIOR_LV0 -2.0f
#define IV0 7.389056098930650f  /* exp(2.0) */

// ws layout (floats):
//   [0, 4096)      : Bsw — 16 KB bf16 MFMA B-fragments
//                    frag-set s = kc*4+tile; lane l: 8 bf16 =
//                    B[kc*32 + (l>>4)*8 + j][tile*16 + (l&15)], j=0..7
//                    B[j][k] = j<64 ? P'[k][d=j] : Q[k][d=j-64]
//   [4096, 4160)   : c[k]
//   [4160, 4224)   : logpi[k]
//   [4224, 8320)   : per-block LSE partials (NBLOCKS floats) — written by
//                    gmm_main AFTER setup is done, overlapping the staging
//                    region below (setup-only) is safe.
//   [4224, 12416)  : fp32 P/Q staging (setup_frags only): P' at
//                    4224+d*128+k, Q at 4224+d*128+64+k

#define WS_C     4096
#define WS_LPI   4160
#define WS_PART  4224
#define WS_STAGE 4224

typedef __attribute__((ext_vector_type(8))) short short8;
typedef __attribute__((ext_vector_type(4))) float floatx4;

static __device__ inline unsigned short f2bf_bits(float f) {
  union { float f; unsigned u; } v; v.f = f;
  unsigned r = v.u + 0x7fffu + ((v.u >> 16) & 1u);  // RNE
  return (unsigned short)(r >> 16);
}

__global__ __launch_bounds__(256) void setup_frags(
    const float* __restrict__ u_noise, const float* __restrict__ phi_logits,
    const float* __restrict__ q_mu, const float* __restrict__ q_logvar,
    const float* __restrict__ pi_logits, float* __restrict__ ws) {
  __shared__ float sPhi[DDIM];
  __shared__ float sR[DDIM];
  __shared__ float sBeta;
  __shared__ float sPart[4][KDIM];
  int tid = threadIdx.x;

  if (tid < 64) {  // exactly wave 0
    int d = tid;
    float u = u_noise[d];
    float g = -__logf(-__logf(u + 1e-9f) + 1e-9f);
    float phi = 1.0f / (1.0f + __expf(-(phi_logits[d] + g)));  // TEMP=1
    sPhi[d] = phi;
    sR[d] = -0.5f * (1.0f - phi) * IV0;

    float betap = -0.5f * (1.0f - phi) * (LOG2PI + PRIOR_LV0);
    #pragma unroll
    for (int o = 1; o < 64; o <<= 1) betap += __shfl_xor(betap, o, 64);
    if (d == 0) sBeta = betap;

    // log(softmax(pi_logits) + 1e-9)
    float l = pi_logits[d];
    float m = l;
    #pragma unroll
    for (int o = 1; o < 64; o <<= 1) m = fmaxf(m, __shfl_xor(m, o, 64));
    float e = __expf(l - m);
    float s = e;
    #pragma unroll
    for (int o = 1; o < 64; o <<= 1) s += __shfl_xor(s, o, 64);
    ws[WS_LPI + d] = __logf(e / s + 1e-9f);
  }
  __syncthreads();

  int k = tid & 63, seg = tid >> 6;
  float ap = 0.0f;
  for (int dd = 0; dd < 16; ++dd) {
    int d = seg * 16 + dd;
    float lv = fminf(fmaxf(q_logvar[k * DDIM + d], -5.0f), 5.0f);
    float iv = __expf(-lv);
    float a = sPhi[d] * iv;
    float mu = q_mu[k * DDIM + d];
    ws[WS_STAGE + d * 128 + k]      = -0.5f * a + sR[d];  // P'
    ws[WS_STAGE + d * 128 + 64 + k] = mu * a;             // Q
    ap += sPhi[d] * (LOG2PI + lv) + mu * mu * a;
  }
  sPart[seg][k] = ap;
  __syncthreads();
  if (tid < 64) {
    float alpha = sPart[0][tid] + sPart[1][tid] + sPart[2][tid] + sPart[3][tid];
    ws[WS_C + tid] = -0.5f * alpha + sBeta;  // c_k
  }

  // B-fragment swizzle for mfma_f32_16x16x32_bf16
  unsigned short* bsw = (unsigned short*)ws;
  #pragma unroll
  for (int p = 0; p < 4; ++p) {
    int pr = p * 256 + tid;       // 0..1023 = frag-set*64 + lane
    int s  = pr >> 6;
    int l  = pr & 63;
    int kc = s >> 2, tl = s & 3;
    int q  = l >> 4, nn = l & 15;
    int col = tl * 16 + nn;
    int bk  = kc * 32 + q * 8;
    #pragma unroll
    for (int j = 0; j < 8; ++j) {
      int r = bk + j;
      float val = (r < 64) ? ws[WS_STAGE + r * 128 + col]
                           : ws[WS_STAGE + (r - 64) * 128 + 64 + col];
      bsw[pr * 8 + j] = f2bf_bits(val);
    }
  }
}

// Flat main kernel: 4096 blocks x 4 waves, one 16-row tile per wave.
// B-fragments read from global ws (L1-resident per CU). No atomics:
// per-block partial -> ws[WS_PART + blockIdx].
__global__ __launch_bounds__(256, 4) void gmm_main(
    const float* __restrict__ X, const float* __restrict__ ws,
    float* __restrict__ out) {
  __shared__ float sRed[4];
  int tid  = threadIdx.x;
  int lane = tid & 63;
  int w    = tid >> 6;
  int n    = lane & 15;   // A-row within tile == C/D column within tile
  int q    = lane >> 4;   // quad
  long rbase = ((long)blockIdx.x * 4 + w) * 16;

  // ---- X fragment loads: row rbase+n, d in [q*8,q*8+8) and [32+q*8,...)
  const float* xr = X + (rbase + n) * DDIM;
  float4 xa0 = *(const float4*)(xr + q * 8);
  float4 xa1 = *(const float4*)(xr + q * 8 + 4);
  float4 xb0 = *(const float4*)(xr + 32 + q * 8);
  float4 xb1 = *(const float4*)(xr + 32 + q * 8 + 4);

  // ---- A fragments: kc0 = x^2 lo, kc1 = x^2 hi, kc2 = x lo, kc3 = x hi
  short8 a[4];
  {
    float xa[8] = {xa0.x, xa0.y, xa0.z, xa0.w, xa1.x, xa1.y, xa1.z, xa1.w};
    float xb[8] = {xb0.x, xb0.y, xb0.z, xb0.w, xb1.x, xb1.y, xb1.z, xb1.w};
    #pragma unroll
    for (int j = 0; j < 8; ++j) {
      a[0][j] = (short)f2bf_bits(xa[j] * xa[j]);
      a[1][j] = (short)f2bf_bits(xb[j] * xb[j]);
      a[2][j] = (short)f2bf_bits(xa[j]);
      a[3][j] = (short)f2bf_bits(xb[j]);
    }
  }

  // ---- MFMA: 4 k-chunks x 4 col-tiles
  const short8* Bf = (const short8*)ws;
  floatx4 acc[4];
  #pragma unroll
  for (int t = 0; t < 4; ++t) acc[t] = (floatx4){0.f, 0.f, 0.f, 0.f};
  #pragma unroll
  for (int kc = 0; kc < 4; ++kc) {
    #pragma unroll
    for (int t = 0; t < 4; ++t) {
      short8 b = Bf[(kc * 4 + t) * 64 + lane];
      acc[t] = __builtin_amdgcn_mfma_f32_16x16x32_bf16(a[kc], b, acc[t], 0, 0, 0);
    }
  }

  // ---- epilogue: bias + store log_p + LSE reduce
  float cb[4], lpi[4];
  #pragma unroll
  for (int t = 0; t < 4; ++t) {
    cb[t]  = ws[WS_C + t * 16 + n];
    lpi[t] = ws[WS_LPI + t * 16 + n];
  }
  float* lp = out + 1 + DDIM;  // float-offset 65
  float rowacc = 0.0f;
  #pragma unroll
  for (int reg = 0; reg < 4; ++reg) {
    long row = rbase + q * 4 + reg;  // C/D row = quad*4 + reg
    float o0 = acc[0][reg] + cb[0];
    float o1 = acc[1][reg] + cb[1];
    float o2 = acc[2][reg] + cb[2];
    float o3 = acc[3][reg] + cb[3];
    long off = row * KDIM + n;
    lp[off]      = o0;
    lp[off + 16] = o1;
    lp[off + 32] = o2;
    lp[off + 48] = o3;
    float v0 = o0 + lpi[0], v1 = o1 + lpi[1], v2 = o2 + lpi[2], v3 = o3 + lpi[3];
    float m = fmaxf(fmaxf(v0, v1), fmaxf(v2, v3));
    #pragma unroll
    for (int o = 1; o <= 8; o <<= 1) m = fmaxf(m, __shfl_xor(m, o, 64));
    float s = __expf(v0 - m) + __expf(v1 - m) + __expf(v2 - m) + __expf(v3 - m);
    #pragma unroll
    for (int o = 1; o <= 8; o <<= 1) s += __shfl_xor(s, o, 64);
    if (n == 0) rowacc += m + __logf(s);
  }
  // wave partial (lanes 0,16,32,48 hold rows) -> LDS -> one plain store
  float t2 = (n == 0) ? rowacc : 0.0f;
  t2 += __shfl_xor(t2, 16, 64);
  t2 += __shfl_xor(t2, 32, 64);
  if (lane == 0) sRed[w] = t2;
  __syncthreads();
  if (tid == 0) {
    float* wsp = (float*)ws;  // un-const for the partial write
    wsp[WS_PART + blockIdx.x] = sRed[0] + sRed[1] + sRed[2] + sRed[3];
  }
}

// Final: sum 4096 partials, kl_phi, q_phi, write out[0], out[1..64].
__global__ __launch_bounds__(256) void finalize_kernel(
    const float* __restrict__ phi_logits, const float* __restrict__ prior_p,
    const float* __restrict__ ws, float* __restrict__ out) {
  __shared__ float sW[4];
  __shared__ float sKl;
  int tid = threadIdx.x;
  int lane = tid & 63, w = tid >> 6;

  float s = 0.0f;
  #pragma unroll
  for (int i = 0; i < NBLOCKS / 256; ++i)
    s += ws[WS_PART + i * 256 + tid];
  #pragma unroll
  for (int o = 1; o < 64; o <<= 1) s += __shfl_xor(s, o, 64);
  if (lane == 0) sW[w] = s;

  if (tid < 64) {
    int d = tid;
    float qp = 1.0f / (1.0f + __expf(-phi_logits[d]));
    qp = fminf(fmaxf(qp, 1e-6f), 1.0f - 1e-6f);
    out[1 + d] = qp;
    float pp = fminf(fmaxf(prior_p[d], 1e-6f), 1.0f - 1e-6f);
    float klp = qp * (__logf(qp) - __logf(pp)) +
                (1.0f - qp) * (__logf(1.0f - qp) - __logf(1.0f - pp));
    #pragma unroll
    for (int o = 1; o < 64; o <<= 1) klp += __shfl_xor(klp, o, 64);
    if (d == 0) sKl = klp * (float)N_SAMPLES;
  }
  __syncthreads();
  if (tid == 0) out[0] = sKl - (sW[0] + sW[1] + sW[2] + sW[3]);
}

extern "C" void kernel_launch(void* const* d_in, const int* in_sizes, int n_in,
                              void* d_out, int out_size, void* d_ws, size_t ws_size,
                              hipStream_t stream) {
  const float* X           = (const float*)d_in[0];
  const float* u_noise     = (const float*)d_in[1];
  const float* phi_logits  = (const float*)d_in[2];
  const float* q_mu        = (const float*)d_in[3];
  const float* q_logvar    = (const float*)d_in[4];
  const float* pi_logits   = (const float*)d_in[5];
  const float* prior_p     = (const float*)d_in[6];
  float* out = (float*)d_out;
  float* ws  = (float*)d_ws;

  setup_frags<<<1, 256, 0, stream>>>(u_noise, phi_logits, q_mu, q_logvar,
                                     pi_logits, ws);
  gmm_main<<<NBLOCKS, 256, 0, stream>>>(X, ws, out);
  finalize_kernel<<<1, 256, 0, stream>>>(phi_logits, prior_p, ws, out);
}